// Round 4
// baseline (250.163 us; speedup 1.0000x reference)
//
#include <hip/hip_runtime.h>

// ---------------------------------------------------------------------------
// EntropyPrunedSelfAttention  (B=4, N=1024, C=768, H=12, hd=64)
// Round 4: fused stats kernel with kg_qkv-style LDS staging (2 passes over K
// chunks: rowZ then column stats), partial-buffer reduction instead of global
// atomics, keep==0 short-circuit for AV/proj.
//
// Workspace (byte offsets):
//   xb      bf16[4096*768]      @ 0
//   qwb     bf16[2304*768]      @ 6291456
//   pwb     bf16[768*768]       @ 9830400
//   qb      bf16[48*1024*64]    @ 11010048
//   kb      bf16[48*1024*64]    @ 17301504
//   v       f32 [48*1024*64]    @ 23592960
//   ctxb    bf16[4096*768]      @ 36175872
//   lse     f32 [48*1024]       @ 42467328
//   mask    f32 [1024]          @ 42663936
//   keep    int [1]             @ 42668032
//   partial f32 [768*2048]      @ 42668544
// total ~46.7 MB (round-1 used 50.5 MB successfully)
// ---------------------------------------------------------------------------

typedef __bf16 bf16x8 __attribute__((ext_vector_type(8)));
typedef __bf16 bf16x4 __attribute__((ext_vector_type(4)));
typedef float  f32x4  __attribute__((ext_vector_type(4)));

#define MFMA16(a, b, c) __builtin_amdgcn_mfma_f32_16x16x32_bf16((a), (b), (c), 0, 0, 0)

// --- 1. fp32 -> bf16 conversion + zero keepCnt -----------------------------
__global__ __launch_bounds__(256) void kc_conv(
    const float* __restrict__ x, const float* __restrict__ qw, const float* __restrict__ pw,
    __bf16* __restrict__ xb, __bf16* __restrict__ qwb, __bf16* __restrict__ pwb,
    int* __restrict__ keepCnt)
{
  const int i = blockIdx.x * 256 + threadIdx.x;
  const float4* src;
  __bf16* dst;
  int j;
  if (i < 786432)       { src = (const float4*)x;  dst = xb;  j = i; }
  else if (i < 1228800) { src = (const float4*)qw; dst = qwb; j = i - 786432; }
  else                  { src = (const float4*)pw; dst = pwb; j = i - 1228800; }
  const float4 f = src[j];
  bf16x4 o;
  o[0] = (__bf16)f.x; o[1] = (__bf16)f.y; o[2] = (__bf16)f.z; o[3] = (__bf16)f.w;
  *(bf16x4*)(dst + 4 * (size_t)j) = o;
  if (i == 0) *keepCnt = 0;
}

// --- 2. QKV GEMM (software-pipelined): qkv = xb @ qwb.T --------------------
__global__ __launch_bounds__(256) void kg_qkv(
    const __bf16* __restrict__ A, const __bf16* __restrict__ Bm,
    __bf16* __restrict__ qb, __bf16* __restrict__ kb, float* __restrict__ v)
{
  __shared__ __bf16 As[64 * 72];
  __shared__ __bf16 Bs[64 * 72];
  const int tid = threadIdx.x;
  const int w = tid >> 6, lane = tid & 63, quad = lane >> 4, l = lane & 15;
  const int r0 = blockIdx.y * 64, c0 = blockIdx.x * 64;
  const int row = tid >> 3, ko = (tid & 7) * 8;
  const f32x4 zero = {0.f, 0.f, 0.f, 0.f};
  f32x4 acc[4];
#pragma unroll
  for (int ct = 0; ct < 4; ++ct) acc[ct] = zero;

  uint4 a0 = *(const uint4*)(A + (size_t)(r0 + row) * 768 + ko);
  uint4 a1 = *(const uint4*)(A + (size_t)(r0 + row + 32) * 768 + ko);
  uint4 b0 = *(const uint4*)(Bm + (size_t)(c0 + row) * 768 + ko);
  uint4 b1 = *(const uint4*)(Bm + (size_t)(c0 + row + 32) * 768 + ko);

  for (int k0 = 0; k0 < 768; k0 += 64) {
    __syncthreads();
    *(uint4*)&As[row * 72 + ko] = a0;
    *(uint4*)&As[(row + 32) * 72 + ko] = a1;
    *(uint4*)&Bs[row * 72 + ko] = b0;
    *(uint4*)&Bs[(row + 32) * 72 + ko] = b1;
    __syncthreads();
    if (k0 < 704) {
      a0 = *(const uint4*)(A + (size_t)(r0 + row) * 768 + k0 + 64 + ko);
      a1 = *(const uint4*)(A + (size_t)(r0 + row + 32) * 768 + k0 + 64 + ko);
      b0 = *(const uint4*)(Bm + (size_t)(c0 + row) * 768 + k0 + 64 + ko);
      b1 = *(const uint4*)(Bm + (size_t)(c0 + row + 32) * 768 + k0 + 64 + ko);
    }
    const bf16x8 af0 = *(const bf16x8*)&As[(w * 16 + l) * 72 + quad * 8];
    const bf16x8 af1 = *(const bf16x8*)&As[(w * 16 + l) * 72 + 32 + quad * 8];
#pragma unroll
    for (int ct = 0; ct < 4; ++ct) {
      const bf16x8 bf0 = *(const bf16x8*)&Bs[(ct * 16 + l) * 72 + quad * 8];
      const bf16x8 bf1 = *(const bf16x8*)&Bs[(ct * 16 + l) * 72 + 32 + quad * 8];
      acc[ct] = MFMA16(af0, bf0, acc[ct]);
      acc[ct] = MFMA16(af1, bf1, acc[ct]);
    }
  }
  const int part = c0 / 768;
  const int h = (c0 % 768) >> 6;
#pragma unroll
  for (int ct = 0; ct < 4; ++ct) {
    const int d = ct * 16 + l;
#pragma unroll
    for (int i = 0; i < 4; ++i) {
      const int rg = r0 + w * 16 + quad * 4 + i;
      const int b_ = rg >> 10, n = rg & 1023;
      const size_t off = ((size_t)(b_ * 12 + h) * 1024 + n) * 64 + d;
      const float val = acc[ct][i];
      if (part == 0)      qb[off] = (__bf16)val;
      else if (part == 1) kb[off] = (__bf16)val;
      else                v[off]  = val;
    }
  }
}

// --- 3. fused stats: pass1 rowZ (exact, in-block) -> lse, pass2 col stats --
// grid (48, 16): block = (bh, 64 rows) x all 1024 cols; K chunks staged in LDS.
__global__ __launch_bounds__(256) void ks_fused(
    const __bf16* __restrict__ qb, const __bf16* __restrict__ kb,
    float* __restrict__ lse, float* __restrict__ partial)
{
  __shared__ __bf16 Ks[64 * 72];
  __shared__ float sS[1024];
  __shared__ float sP[1024];
  const int tid = threadIdx.x;
  const int w = tid >> 6, lane = tid & 63, quad = lane >> 4, l = lane & 15;
  const int bh = blockIdx.x, r0 = blockIdx.y * 64;
  const int row = tid >> 3, ko = (tid & 7) * 8;
  for (int i = tid; i < 1024; i += 256) { sS[i] = 0.f; sP[i] = 0.f; }

  const __bf16* qrow = qb + ((size_t)bh * 1024 + r0 + w * 16 + l) * 64;
  const bf16x8 aq0 = *(const bf16x8*)(qrow + quad * 8);
  const bf16x8 aq1 = *(const bf16x8*)(qrow + 32 + quad * 8);
  const __bf16* kbase = kb + (size_t)bh * 65536;  // [1024][64]
  const f32x4 zero = {0.f, 0.f, 0.f, 0.f};

  uint4 ka0 = *(const uint4*)(kbase + (size_t)row * 64 + ko);
  uint4 ka1 = *(const uint4*)(kbase + (size_t)(row + 32) * 64 + ko);

  float z[4] = {0.f, 0.f, 0.f, 0.f};
  // ---- pass 1: row sums of exp ----
  for (int chunk = 0; chunk < 16; ++chunk) {
    __syncthreads();
    *(uint4*)&Ks[row * 72 + ko] = ka0;
    *(uint4*)&Ks[(row + 32) * 72 + ko] = ka1;
    __syncthreads();
    const int nxt = (chunk < 15) ? (chunk + 1) : 0;  // chunk 15 prefetches pass-2 chunk 0
    ka0 = *(const uint4*)(kbase + (size_t)(nxt * 64 + row) * 64 + ko);
    ka1 = *(const uint4*)(kbase + (size_t)(nxt * 64 + row + 32) * 64 + ko);
#pragma unroll
    for (int ct = 0; ct < 4; ++ct) {
      const bf16x8 kf0 = *(const bf16x8*)&Ks[(ct * 16 + l) * 72 + quad * 8];
      const bf16x8 kf1 = *(const bf16x8*)&Ks[(ct * 16 + l) * 72 + 32 + quad * 8];
      f32x4 acc = MFMA16(aq0, kf0, zero);
      acc = MFMA16(aq1, kf1, acc);
#pragma unroll
      for (int r = 0; r < 4; ++r) z[r] += __expf(acc[r] * 0.125f);
    }
  }
  // reduce over the 16 column-lanes (xor within quad group); all lanes get sum
#pragma unroll
  for (int off = 1; off < 16; off <<= 1) {
#pragma unroll
    for (int r = 0; r < 4; ++r) z[r] += __shfl_xor(z[r], off);
  }
  float ls[4];
#pragma unroll
  for (int r = 0; r < 4; ++r) ls[r] = __logf(z[r]);
  if (l == 0) {
#pragma unroll
    for (int r = 0; r < 4; ++r)
      lse[bh * 1024 + r0 + w * 16 + quad * 4 + r] = ls[r];
  }

  // ---- pass 2: column sums of p and p*logp ----
  for (int chunk = 0; chunk < 16; ++chunk) {
    __syncthreads();
    *(uint4*)&Ks[row * 72 + ko] = ka0;
    *(uint4*)&Ks[(row + 32) * 72 + ko] = ka1;
    __syncthreads();
    if (chunk < 15) {
      ka0 = *(const uint4*)(kbase + (size_t)((chunk + 1) * 64 + row) * 64 + ko);
      ka1 = *(const uint4*)(kbase + (size_t)((chunk + 1) * 64 + row + 32) * 64 + ko);
    }
#pragma unroll
    for (int ct = 0; ct < 4; ++ct) {
      const bf16x8 kf0 = *(const bf16x8*)&Ks[(ct * 16 + l) * 72 + quad * 8];
      const bf16x8 kf1 = *(const bf16x8*)&Ks[(ct * 16 + l) * 72 + 32 + quad * 8];
      f32x4 acc = MFMA16(aq0, kf0, zero);
      acc = MFMA16(aq1, kf1, acc);
      float sp = 0.f, spl = 0.f;
#pragma unroll
      for (int r = 0; r < 4; ++r) {
        const float lp = acc[r] * 0.125f - ls[r];
        const float p = __expf(lp);
        sp += p;
        spl += p * lp;
      }
      // sum over the 4 quads (rows) -> lanes<16 hold column partials
      sp += __shfl_xor(sp, 16);   sp += __shfl_xor(sp, 32);
      spl += __shfl_xor(spl, 16); spl += __shfl_xor(spl, 32);
      if (lane < 16) {
        atomicAdd(&sS[chunk * 64 + ct * 16 + l], sp);   // 4-way (waves), LDS
        atomicAdd(&sP[chunk * 64 + ct * 16 + l], spl);
      }
    }
  }
  __syncthreads();
  float* pb = partial + (size_t)(blockIdx.x * 16 + blockIdx.y) * 2048;
  for (int i = tid; i < 1024; i += 256) {
    pb[i] = sS[i];
    pb[1024 + i] = sP[i];
  }
}

// --- 4. reduce partials -> entropy -> mask + keepCnt -----------------------
// grid (4, 256): thread j handles column j.
__global__ __launch_bounds__(256) void k_maskred(
    const float* __restrict__ partial, const int* __restrict__ cur_epoch,
    float* __restrict__ mask, int* __restrict__ keepCnt)
{
  const int j = blockIdx.x * 256 + threadIdx.x;
  float s = 0.f, plp = 0.f;
#pragma unroll 4
  for (int p = 0; p < 768; ++p) {
    s   += partial[(size_t)p * 2048 + j];
    plp += partial[(size_t)p * 2048 + 1024 + j];
  }
  const float ent = __logf(s) - plp / s;
  const int ce = cur_epoch[0];
  float factor = 0.f;
  for (int i = 1; i <= ce; ++i) factor += __expf(-(float)i);
  factor *= 5.0f;
  const float thr = __logf(768.0f) - factor;
  const int keep = (ent <= thr) ? 1 : 0;
  mask[j] = keep ? 1.0f : 0.0f;
  if (keep) atomicAdd(keepCnt, 1);
}

// --- 5. masked AV -> ctxb (bf16). No-op when no column survives. -----------
__global__ __launch_bounds__(256) void k_av(
    const __bf16* __restrict__ qb, const __bf16* __restrict__ kb,
    const float* __restrict__ v, const float* __restrict__ lse,
    const float* __restrict__ mask, const int* __restrict__ keepCnt,
    __bf16* __restrict__ ctxb)
{
  if (*keepCnt == 0) return;  // ctxb unused downstream in this case
  const int tid = threadIdx.x;
  const int bh = blockIdx.x, r0 = blockIdx.y * 32;
  const int b_ = bh / 12, h = bh % 12;
  // general path (not taken for the graded input)
  __shared__ float qs[32][64];
  __shared__ float pbuf[4][8][64];
  for (int i = tid; i < 2048; i += 256)
    qs[i >> 6][i & 63] = (float)qb[((size_t)bh * 1024 + r0) * 64 + i];
  __syncthreads();
  const int w = tid >> 6, l = tid & 63, rb = w * 8;
  float ls[8];
#pragma unroll
  for (int i = 0; i < 8; ++i) ls[i] = lse[bh * 1024 + r0 + rb + i];
  float acc[8] = {};
  for (int chunk = 0; chunk < 16; ++chunk) {
    const float mk = mask[chunk * 64 + l];
    if (__ballot(mk != 0.0f) == 0ull) continue;  // block-uniform
    const __bf16* kp = kb + ((size_t)bh * 1024 + chunk * 64 + l) * 64;
    float s[8] = {};
    for (int d0 = 0; d0 < 64; d0 += 8) {
      const bf16x8 kf = *(const bf16x8*)(kp + d0);
#pragma unroll
      for (int dd = 0; dd < 8; ++dd) {
        const float kv = (float)kf[dd];
#pragma unroll
        for (int i = 0; i < 8; ++i) s[i] += qs[rb + i][d0 + dd] * kv;
      }
    }
    __syncthreads();
#pragma unroll
    for (int i = 0; i < 8; ++i)
      pbuf[w][i][l] = __expf(s[i] * 0.125f - ls[i]) * mk;
    __syncthreads();
    const float* vp = v + ((size_t)bh * 1024 + chunk * 64) * 64 + l;
    for (int jj = 0; jj < 64; ++jj) {
      const float vv = vp[(size_t)jj * 64];
#pragma unroll
      for (int i = 0; i < 8; ++i) acc[i] += pbuf[w][i][jj] * vv;
    }
  }
#pragma unroll
  for (int i = 0; i < 8; ++i)
    ctxb[((size_t)(b_ * 1024 + r0 + rb + i)) * 768 + h * 64 + l] = (__bf16)acc[i];
}

// --- 6. proj GEMM: out = ctxb @ pwb.T + bias; bias-only when keep==0 -------
__global__ __launch_bounds__(256) void kg_proj(
    const __bf16* __restrict__ A, const __bf16* __restrict__ Bm,
    const float* __restrict__ bias, const int* __restrict__ keepCnt,
    float* __restrict__ out)
{
  const int tid = threadIdx.x;
  const int w = tid >> 6, lane = tid & 63, quad = lane >> 4, l = lane & 15;
  const int r0 = blockIdx.y * 64, c0 = blockIdx.x * 64;
  if (*keepCnt == 0) {  // ctx == 0 -> out = bias (uniform branch)
#pragma unroll
    for (int ct = 0; ct < 4; ++ct) {
      const int c = c0 + ct * 16 + l;
      const float bv = bias[c];
#pragma unroll
      for (int i = 0; i < 4; ++i) {
        const int rg = r0 + w * 16 + quad * 4 + i;
        out[(size_t)rg * 768 + c] = bv;
      }
    }
    return;
  }
  __shared__ __bf16 As[64 * 72];
  __shared__ __bf16 Bs[64 * 72];
  const int row = tid >> 3, ko = (tid & 7) * 8;
  const f32x4 zero = {0.f, 0.f, 0.f, 0.f};
  f32x4 acc[4];
#pragma unroll
  for (int ct = 0; ct < 4; ++ct) acc[ct] = zero;

  uint4 a0 = *(const uint4*)(A + (size_t)(r0 + row) * 768 + ko);
  uint4 a1 = *(const uint4*)(A + (size_t)(r0 + row + 32) * 768 + ko);
  uint4 b0 = *(const uint4*)(Bm + (size_t)(c0 + row) * 768 + ko);
  uint4 b1 = *(const uint4*)(Bm + (size_t)(c0 + row + 32) * 768 + ko);

  for (int k0 = 0; k0 < 768; k0 += 64) {
    __syncthreads();
    *(uint4*)&As[row * 72 + ko] = a0;
    *(uint4*)&As[(row + 32) * 72 + ko] = a1;
    *(uint4*)&Bs[row * 72 + ko] = b0;
    *(uint4*)&Bs[(row + 32) * 72 + ko] = b1;
    __syncthreads();
    if (k0 < 704) {
      a0 = *(const uint4*)(A + (size_t)(r0 + row) * 768 + k0 + 64 + ko);
      a1 = *(const uint4*)(A + (size_t)(r0 + row + 32) * 768 + k0 + 64 + ko);
      b0 = *(const uint4*)(Bm + (size_t)(c0 + row) * 768 + k0 + 64 + ko);
      b1 = *(const uint4*)(Bm + (size_t)(c0 + row + 32) * 768 + k0 + 64 + ko);
    }
    const bf16x8 af0 = *(const bf16x8*)&As[(w * 16 + l) * 72 + quad * 8];
    const bf16x8 af1 = *(const bf16x8*)&As[(w * 16 + l) * 72 + 32 + quad * 8];
#pragma unroll
    for (int ct = 0; ct < 4; ++ct) {
      const bf16x8 bf0 = *(const bf16x8*)&Bs[(ct * 16 + l) * 72 + quad * 8];
      const bf16x8 bf1 = *(const bf16x8*)&Bs[(ct * 16 + l) * 72 + 32 + quad * 8];
      acc[ct] = MFMA16(af0, bf0, acc[ct]);
      acc[ct] = MFMA16(af1, bf1, acc[ct]);
    }
  }
#pragma unroll
  for (int ct = 0; ct < 4; ++ct) {
    const int c = c0 + ct * 16 + l;
#pragma unroll
    for (int i = 0; i < 4; ++i) {
      const int rg = r0 + w * 16 + quad * 4 + i;
      out[(size_t)rg * 768 + c] = acc[ct][i] + bias[c];
    }
  }
}

extern "C" void kernel_launch(void* const* d_in, const int* in_sizes, int n_in,
                              void* d_out, int out_size, void* d_ws, size_t ws_size,
                              hipStream_t stream)
{
  const float* x      = (const float*)d_in[0];
  const float* qkv_w  = (const float*)d_in[1];
  const float* proj_w = (const float*)d_in[2];
  const float* proj_b = (const float*)d_in[3];
  const int*   cur_ep = (const int*)d_in[4];

  char* W = (char*)d_ws;
  __bf16* xb   = (__bf16*)(W + 0);
  __bf16* qwb  = (__bf16*)(W + 6291456);
  __bf16* pwb  = (__bf16*)(W + 9830400);
  __bf16* qb   = (__bf16*)(W + 11010048);
  __bf16* kb   = (__bf16*)(W + 17301504);
  float*  v    = (float*) (W + 23592960);
  __bf16* ctxb = (__bf16*)(W + 36175872);
  float*  lse  = (float*) (W + 42467328);
  float*  mask = (float*) (W + 42663936);
  int*    keep = (int*)   (W + 42668032);
  float*  part = (float*) (W + 42668544);
  float*  out  = (float*)d_out;

  kc_conv<<<5376, 256, 0, stream>>>(x, qkv_w, proj_w, xb, qwb, pwb, keep);
  kg_qkv<<<dim3(36, 64), 256, 0, stream>>>(xb, qwb, qb, kb, v);
  ks_fused<<<dim3(48, 16), 256, 0, stream>>>(qb, kb, lse, part);
  k_maskred<<<4, 256, 0, stream>>>(part, cur_ep, mask, keep);
  k_av<<<dim3(48, 32), 256, 0, stream>>>(qb, kb, v, lse, mask, keep, ctxb);
  kg_proj<<<dim3(12, 64), 256, 0, stream>>>(ctxb, pwb, proj_b, keep, out);
}

// Round 5
// 179.934 us; speedup vs baseline: 1.3903x; 1.3903x over previous
//
#include <hip/hip_runtime.h>

// ---------------------------------------------------------------------------
// EntropyPrunedSelfAttention  (B=4, N=1024, C=768, H=12, hd=64)
// Round 5: fix the partial reduction (round-4's 75us latency-bound k_maskred):
// kr_reduce grid(48,8) coalesced 16-row sums + atomicAdd into colSP[2048],
// then a tiny k_mask. Everything else identical to round 4.
//
// Workspace (byte offsets):
//   xb      bf16[4096*768]      @ 0
//   qwb     bf16[2304*768]      @ 6291456
//   pwb     bf16[768*768]       @ 9830400
//   qb      bf16[48*1024*64]    @ 11010048
//   kb      bf16[48*1024*64]    @ 17301504
//   v       f32 [48*1024*64]    @ 23592960
//   ctxb    bf16[4096*768]      @ 36175872
//   lse     f32 [48*1024]       @ 42467328
//   mask    f32 [1024]          @ 42663936
//   keep    int [1]             @ 42668032
//   colSP   f32 [2048]          @ 42668544   (colS[1024] ++ colP[1024])
//   partial f32 [768*2048]      @ 42676736
// total ~46.7 MB
// ---------------------------------------------------------------------------

typedef __bf16 bf16x8 __attribute__((ext_vector_type(8)));
typedef __bf16 bf16x4 __attribute__((ext_vector_type(4)));
typedef float  f32x4  __attribute__((ext_vector_type(4)));

#define MFMA16(a, b, c) __builtin_amdgcn_mfma_f32_16x16x32_bf16((a), (b), (c), 0, 0, 0)

// --- 1. fp32 -> bf16 conversion + zero colSP/keepCnt -----------------------
__global__ __launch_bounds__(256) void kc_conv(
    const float* __restrict__ x, const float* __restrict__ qw, const float* __restrict__ pw,
    __bf16* __restrict__ xb, __bf16* __restrict__ qwb, __bf16* __restrict__ pwb,
    float* __restrict__ colSP, int* __restrict__ keepCnt)
{
  const int i = blockIdx.x * 256 + threadIdx.x;
  const float4* src;
  __bf16* dst;
  int j;
  if (i < 786432)       { src = (const float4*)x;  dst = xb;  j = i; }
  else if (i < 1228800) { src = (const float4*)qw; dst = qwb; j = i - 786432; }
  else                  { src = (const float4*)pw; dst = pwb; j = i - 1228800; }
  const float4 f = src[j];
  bf16x4 o;
  o[0] = (__bf16)f.x; o[1] = (__bf16)f.y; o[2] = (__bf16)f.z; o[3] = (__bf16)f.w;
  *(bf16x4*)(dst + 4 * (size_t)j) = o;
  if (i < 2048) colSP[i] = 0.f;
  if (i == 0) *keepCnt = 0;
}

// --- 2. QKV GEMM (software-pipelined): qkv = xb @ qwb.T --------------------
__global__ __launch_bounds__(256) void kg_qkv(
    const __bf16* __restrict__ A, const __bf16* __restrict__ Bm,
    __bf16* __restrict__ qb, __bf16* __restrict__ kb, float* __restrict__ v)
{
  __shared__ __bf16 As[64 * 72];
  __shared__ __bf16 Bs[64 * 72];
  const int tid = threadIdx.x;
  const int w = tid >> 6, lane = tid & 63, quad = lane >> 4, l = lane & 15;
  const int r0 = blockIdx.y * 64, c0 = blockIdx.x * 64;
  const int row = tid >> 3, ko = (tid & 7) * 8;
  const f32x4 zero = {0.f, 0.f, 0.f, 0.f};
  f32x4 acc[4];
#pragma unroll
  for (int ct = 0; ct < 4; ++ct) acc[ct] = zero;

  uint4 a0 = *(const uint4*)(A + (size_t)(r0 + row) * 768 + ko);
  uint4 a1 = *(const uint4*)(A + (size_t)(r0 + row + 32) * 768 + ko);
  uint4 b0 = *(const uint4*)(Bm + (size_t)(c0 + row) * 768 + ko);
  uint4 b1 = *(const uint4*)(Bm + (size_t)(c0 + row + 32) * 768 + ko);

  for (int k0 = 0; k0 < 768; k0 += 64) {
    __syncthreads();
    *(uint4*)&As[row * 72 + ko] = a0;
    *(uint4*)&As[(row + 32) * 72 + ko] = a1;
    *(uint4*)&Bs[row * 72 + ko] = b0;
    *(uint4*)&Bs[(row + 32) * 72 + ko] = b1;
    __syncthreads();
    if (k0 < 704) {
      a0 = *(const uint4*)(A + (size_t)(r0 + row) * 768 + k0 + 64 + ko);
      a1 = *(const uint4*)(A + (size_t)(r0 + row + 32) * 768 + k0 + 64 + ko);
      b0 = *(const uint4*)(Bm + (size_t)(c0 + row) * 768 + k0 + 64 + ko);
      b1 = *(const uint4*)(Bm + (size_t)(c0 + row + 32) * 768 + k0 + 64 + ko);
    }
    const bf16x8 af0 = *(const bf16x8*)&As[(w * 16 + l) * 72 + quad * 8];
    const bf16x8 af1 = *(const bf16x8*)&As[(w * 16 + l) * 72 + 32 + quad * 8];
#pragma unroll
    for (int ct = 0; ct < 4; ++ct) {
      const bf16x8 bf0 = *(const bf16x8*)&Bs[(ct * 16 + l) * 72 + quad * 8];
      const bf16x8 bf1 = *(const bf16x8*)&Bs[(ct * 16 + l) * 72 + 32 + quad * 8];
      acc[ct] = MFMA16(af0, bf0, acc[ct]);
      acc[ct] = MFMA16(af1, bf1, acc[ct]);
    }
  }
  const int part = c0 / 768;
  const int h = (c0 % 768) >> 6;
#pragma unroll
  for (int ct = 0; ct < 4; ++ct) {
    const int d = ct * 16 + l;
#pragma unroll
    for (int i = 0; i < 4; ++i) {
      const int rg = r0 + w * 16 + quad * 4 + i;
      const int b_ = rg >> 10, n = rg & 1023;
      const size_t off = ((size_t)(b_ * 12 + h) * 1024 + n) * 64 + d;
      const float val = acc[ct][i];
      if (part == 0)      qb[off] = (__bf16)val;
      else if (part == 1) kb[off] = (__bf16)val;
      else                v[off]  = val;
    }
  }
}

// --- 3. fused stats: pass1 rowZ (exact, in-block) -> lse, pass2 col stats --
// grid (48, 16): block = (bh, 64 rows) x all 1024 cols; K chunks staged in LDS.
__global__ __launch_bounds__(256) void ks_fused(
    const __bf16* __restrict__ qb, const __bf16* __restrict__ kb,
    float* __restrict__ lse, float* __restrict__ partial)
{
  __shared__ __bf16 Ks[64 * 72];
  __shared__ float sS[1024];
  __shared__ float sP[1024];
  const int tid = threadIdx.x;
  const int w = tid >> 6, lane = tid & 63, quad = lane >> 4, l = lane & 15;
  const int bh = blockIdx.x, r0 = blockIdx.y * 64;
  const int row = tid >> 3, ko = (tid & 7) * 8;
  for (int i = tid; i < 1024; i += 256) { sS[i] = 0.f; sP[i] = 0.f; }

  const __bf16* qrow = qb + ((size_t)bh * 1024 + r0 + w * 16 + l) * 64;
  const bf16x8 aq0 = *(const bf16x8*)(qrow + quad * 8);
  const bf16x8 aq1 = *(const bf16x8*)(qrow + 32 + quad * 8);
  const __bf16* kbase = kb + (size_t)bh * 65536;  // [1024][64]
  const f32x4 zero = {0.f, 0.f, 0.f, 0.f};

  uint4 ka0 = *(const uint4*)(kbase + (size_t)row * 64 + ko);
  uint4 ka1 = *(const uint4*)(kbase + (size_t)(row + 32) * 64 + ko);

  float z[4] = {0.f, 0.f, 0.f, 0.f};
  // ---- pass 1: row sums of exp ----
  for (int chunk = 0; chunk < 16; ++chunk) {
    __syncthreads();
    *(uint4*)&Ks[row * 72 + ko] = ka0;
    *(uint4*)&Ks[(row + 32) * 72 + ko] = ka1;
    __syncthreads();
    const int nxt = (chunk < 15) ? (chunk + 1) : 0;  // chunk 15 prefetches pass-2 chunk 0
    ka0 = *(const uint4*)(kbase + (size_t)(nxt * 64 + row) * 64 + ko);
    ka1 = *(const uint4*)(kbase + (size_t)(nxt * 64 + row + 32) * 64 + ko);
#pragma unroll
    for (int ct = 0; ct < 4; ++ct) {
      const bf16x8 kf0 = *(const bf16x8*)&Ks[(ct * 16 + l) * 72 + quad * 8];
      const bf16x8 kf1 = *(const bf16x8*)&Ks[(ct * 16 + l) * 72 + 32 + quad * 8];
      f32x4 acc = MFMA16(aq0, kf0, zero);
      acc = MFMA16(aq1, kf1, acc);
#pragma unroll
      for (int r = 0; r < 4; ++r) z[r] += __expf(acc[r] * 0.125f);
    }
  }
#pragma unroll
  for (int off = 1; off < 16; off <<= 1) {
#pragma unroll
    for (int r = 0; r < 4; ++r) z[r] += __shfl_xor(z[r], off);
  }
  float ls[4];
#pragma unroll
  for (int r = 0; r < 4; ++r) ls[r] = __logf(z[r]);
  if (l == 0) {
#pragma unroll
    for (int r = 0; r < 4; ++r)
      lse[bh * 1024 + r0 + w * 16 + quad * 4 + r] = ls[r];
  }

  // ---- pass 2: column sums of p and p*logp ----
  for (int chunk = 0; chunk < 16; ++chunk) {
    __syncthreads();
    *(uint4*)&Ks[row * 72 + ko] = ka0;
    *(uint4*)&Ks[(row + 32) * 72 + ko] = ka1;
    __syncthreads();
    if (chunk < 15) {
      ka0 = *(const uint4*)(kbase + (size_t)((chunk + 1) * 64 + row) * 64 + ko);
      ka1 = *(const uint4*)(kbase + (size_t)((chunk + 1) * 64 + row + 32) * 64 + ko);
    }
#pragma unroll
    for (int ct = 0; ct < 4; ++ct) {
      const bf16x8 kf0 = *(const bf16x8*)&Ks[(ct * 16 + l) * 72 + quad * 8];
      const bf16x8 kf1 = *(const bf16x8*)&Ks[(ct * 16 + l) * 72 + 32 + quad * 8];
      f32x4 acc = MFMA16(aq0, kf0, zero);
      acc = MFMA16(aq1, kf1, acc);
      float sp = 0.f, spl = 0.f;
#pragma unroll
      for (int r = 0; r < 4; ++r) {
        const float lp = acc[r] * 0.125f - ls[r];
        const float p = __expf(lp);
        sp += p;
        spl += p * lp;
      }
      sp += __shfl_xor(sp, 16);   sp += __shfl_xor(sp, 32);
      spl += __shfl_xor(spl, 16); spl += __shfl_xor(spl, 32);
      if (lane < 16) {
        atomicAdd(&sS[chunk * 64 + ct * 16 + l], sp);   // 4-way (waves), LDS
        atomicAdd(&sP[chunk * 64 + ct * 16 + l], spl);
      }
    }
  }
  __syncthreads();
  float* pb = partial + (size_t)(blockIdx.x * 16 + blockIdx.y) * 2048;
  for (int i = tid; i < 1024; i += 256) {
    pb[i] = sS[i];
    pb[1024 + i] = sP[i];
  }
}

// --- 4a. reduce partials: 384 blocks, coalesced, atomic into colSP ---------
// grid (48, 8): block (g, cc) sums partial rows g*16..g*16+15 for columns
// cc*256..cc*256+255 (of the 2048-wide sS++sP row).
__global__ __launch_bounds__(256) void kr_reduce(
    const float* __restrict__ partial, float* __restrict__ colSP)
{
  const int col = blockIdx.y * 256 + threadIdx.x;
  const float* pb = partial + (size_t)blockIdx.x * 16 * 2048 + col;
  float s = 0.f;
#pragma unroll
  for (int p = 0; p < 16; ++p) s += pb[(size_t)p * 2048];
  atomicAdd(&colSP[col], s);
}

// --- 4b. entropy -> mask + keepCnt -----------------------------------------
__global__ void k_mask(const float* __restrict__ colSP, const int* __restrict__ cur_epoch,
                       float* __restrict__ mask, int* __restrict__ keepCnt)
{
  const int j = threadIdx.x;
  const float s = colSP[j];
  const float ent = __logf(s) - colSP[1024 + j] / s;
  const int ce = cur_epoch[0];
  float factor = 0.f;
  for (int i = 1; i <= ce; ++i) factor += __expf(-(float)i);
  factor *= 5.0f;
  const float thr = __logf(768.0f) - factor;
  const int keep = (ent <= thr) ? 1 : 0;
  mask[j] = keep ? 1.0f : 0.0f;
  if (keep) atomicAdd(keepCnt, 1);
}

// --- 5. masked AV -> ctxb (bf16). No-op when no column survives. -----------
__global__ __launch_bounds__(256) void k_av(
    const __bf16* __restrict__ qb, const __bf16* __restrict__ kb,
    const float* __restrict__ v, const float* __restrict__ lse,
    const float* __restrict__ mask, const int* __restrict__ keepCnt,
    __bf16* __restrict__ ctxb)
{
  if (*keepCnt == 0) return;  // ctxb unused downstream in this case
  const int tid = threadIdx.x;
  const int bh = blockIdx.x, r0 = blockIdx.y * 32;
  const int b_ = bh / 12, h = bh % 12;
  __shared__ float qs[32][64];
  __shared__ float pbuf[4][8][64];
  for (int i = tid; i < 2048; i += 256)
    qs[i >> 6][i & 63] = (float)qb[((size_t)bh * 1024 + r0) * 64 + i];
  __syncthreads();
  const int w = tid >> 6, l = tid & 63, rb = w * 8;
  float ls[8];
#pragma unroll
  for (int i = 0; i < 8; ++i) ls[i] = lse[bh * 1024 + r0 + rb + i];
  float acc[8] = {};
  for (int chunk = 0; chunk < 16; ++chunk) {
    const float mk = mask[chunk * 64 + l];
    if (__ballot(mk != 0.0f) == 0ull) continue;  // block-uniform
    const __bf16* kp = kb + ((size_t)bh * 1024 + chunk * 64 + l) * 64;
    float s[8] = {};
    for (int d0 = 0; d0 < 64; d0 += 8) {
      const bf16x8 kf = *(const bf16x8*)(kp + d0);
#pragma unroll
      for (int dd = 0; dd < 8; ++dd) {
        const float kv = (float)kf[dd];
#pragma unroll
        for (int i = 0; i < 8; ++i) s[i] += qs[rb + i][d0 + dd] * kv;
      }
    }
    __syncthreads();
#pragma unroll
    for (int i = 0; i < 8; ++i)
      pbuf[w][i][l] = __expf(s[i] * 0.125f - ls[i]) * mk;
    __syncthreads();
    const float* vp = v + ((size_t)bh * 1024 + chunk * 64) * 64 + l;
    for (int jj = 0; jj < 64; ++jj) {
      const float vv = vp[(size_t)jj * 64];
#pragma unroll
      for (int i = 0; i < 8; ++i) acc[i] += pbuf[w][i][jj] * vv;
    }
  }
#pragma unroll
  for (int i = 0; i < 8; ++i)
    ctxb[((size_t)(b_ * 1024 + r0 + rb + i)) * 768 + h * 64 + l] = (__bf16)acc[i];
}

// --- 6. proj GEMM: out = ctxb @ pwb.T + bias; bias-only when keep==0 -------
__global__ __launch_bounds__(256) void kg_proj(
    const __bf16* __restrict__ A, const __bf16* __restrict__ Bm,
    const float* __restrict__ bias, const int* __restrict__ keepCnt,
    float* __restrict__ out)
{
  const int tid = threadIdx.x;
  const int w = tid >> 6, lane = tid & 63, quad = lane >> 4, l = lane & 15;
  const int r0 = blockIdx.y * 64, c0 = blockIdx.x * 64;
  if (*keepCnt == 0) {  // ctx == 0 -> out = bias (uniform branch)
#pragma unroll
    for (int ct = 0; ct < 4; ++ct) {
      const int c = c0 + ct * 16 + l;
      const float bv = bias[c];
#pragma unroll
      for (int i = 0; i < 4; ++i) {
        const int rg = r0 + w * 16 + quad * 4 + i;
        out[(size_t)rg * 768 + c] = bv;
      }
    }
    return;
  }
  __shared__ __bf16 As[64 * 72];
  __shared__ __bf16 Bs[64 * 72];
  const int row = tid >> 3, ko = (tid & 7) * 8;
  const f32x4 zero = {0.f, 0.f, 0.f, 0.f};
  f32x4 acc[4];
#pragma unroll
  for (int ct = 0; ct < 4; ++ct) acc[ct] = zero;

  uint4 a0 = *(const uint4*)(A + (size_t)(r0 + row) * 768 + ko);
  uint4 a1 = *(const uint4*)(A + (size_t)(r0 + row + 32) * 768 + ko);
  uint4 b0 = *(const uint4*)(Bm + (size_t)(c0 + row) * 768 + ko);
  uint4 b1 = *(const uint4*)(Bm + (size_t)(c0 + row + 32) * 768 + ko);

  for (int k0 = 0; k0 < 768; k0 += 64) {
    __syncthreads();
    *(uint4*)&As[row * 72 + ko] = a0;
    *(uint4*)&As[(row + 32) * 72 + ko] = a1;
    *(uint4*)&Bs[row * 72 + ko] = b0;
    *(uint4*)&Bs[(row + 32) * 72 + ko] = b1;
    __syncthreads();
    if (k0 < 704) {
      a0 = *(const uint4*)(A + (size_t)(r0 + row) * 768 + k0 + 64 + ko);
      a1 = *(const uint4*)(A + (size_t)(r0 + row + 32) * 768 + k0 + 64 + ko);
      b0 = *(const uint4*)(Bm + (size_t)(c0 + row) * 768 + k0 + 64 + ko);
      b1 = *(const uint4*)(Bm + (size_t)(c0 + row + 32) * 768 + k0 + 64 + ko);
    }
    const bf16x8 af0 = *(const bf16x8*)&As[(w * 16 + l) * 72 + quad * 8];
    const bf16x8 af1 = *(const bf16x8*)&As[(w * 16 + l) * 72 + 32 + quad * 8];
#pragma unroll
    for (int ct = 0; ct < 4; ++ct) {
      const bf16x8 bf0 = *(const bf16x8*)&Bs[(ct * 16 + l) * 72 + quad * 8];
      const bf16x8 bf1 = *(const bf16x8*)&Bs[(ct * 16 + l) * 72 + 32 + quad * 8];
      acc[ct] = MFMA16(af0, bf0, acc[ct]);
      acc[ct] = MFMA16(af1, bf1, acc[ct]);
    }
  }
#pragma unroll
  for (int ct = 0; ct < 4; ++ct) {
    const int c = c0 + ct * 16 + l;
#pragma unroll
    for (int i = 0; i < 4; ++i) {
      const int rg = r0 + w * 16 + quad * 4 + i;
      out[(size_t)rg * 768 + c] = acc[ct][i] + bias[c];
    }
  }
}

extern "C" void kernel_launch(void* const* d_in, const int* in_sizes, int n_in,
                              void* d_out, int out_size, void* d_ws, size_t ws_size,
                              hipStream_t stream)
{
  const float* x      = (const float*)d_in[0];
  const float* qkv_w  = (const float*)d_in[1];
  const float* proj_w = (const float*)d_in[2];
  const float* proj_b = (const float*)d_in[3];
  const int*   cur_ep = (const int*)d_in[4];

  char* W = (char*)d_ws;
  __bf16* xb    = (__bf16*)(W + 0);
  __bf16* qwb   = (__bf16*)(W + 6291456);
  __bf16* pwb   = (__bf16*)(W + 9830400);
  __bf16* qb    = (__bf16*)(W + 11010048);
  __bf16* kb    = (__bf16*)(W + 17301504);
  float*  v     = (float*) (W + 23592960);
  __bf16* ctxb  = (__bf16*)(W + 36175872);
  float*  lse   = (float*) (W + 42467328);
  float*  mask  = (float*) (W + 42663936);
  int*    keep  = (int*)   (W + 42668032);
  float*  colSP = (float*) (W + 42668544);
  float*  part  = (float*) (W + 42676736);
  float*  out   = (float*)d_out;

  kc_conv<<<5376, 256, 0, stream>>>(x, qkv_w, proj_w, xb, qwb, pwb, colSP, keep);
  kg_qkv<<<dim3(36, 64), 256, 0, stream>>>(xb, qwb, qb, kb, v);
  ks_fused<<<dim3(48, 16), 256, 0, stream>>>(qb, kb, lse, part);
  kr_reduce<<<dim3(48, 8), 256, 0, stream>>>(part, colSP);
  k_mask<<<1, 1024, 0, stream>>>(colSP, cur_ep, mask, keep);
  k_av<<<dim3(48, 32), 256, 0, stream>>>(qb, kb, v, lse, mask, keep, ctxb);
  kg_proj<<<dim3(12, 64), 256, 0, stream>>>(ctxb, pwb, proj_b, keep, out);
}